// Round 2
// baseline (5545.764 us; speedup 1.0000x reference)
//
#include <hip/hip_runtime.h>
#include <hip/hip_bf16.h>

#define HDIM 32

__device__ __forceinline__ float sigm(float x) {
    return __fdividef(1.0f, 1.0f + __expf(-x));
}
__device__ __forceinline__ float tanh_fast(float x) {
    return 1.0f - __fdividef(2.0f, 1.0f + __expf(2.0f * x));
}

// Layer-0 cell step (input dim 4). All indices compile-time constants after
// unroll; weight addresses wave-uniform -> scalar loads. States by reference
// so SROA keeps them in VGPRs.
__device__ __forceinline__ void l0_step(
    const float* __restrict__ W,   // Wih slice [128*4]
    const float* __restrict__ U,   // Whh slice [128*32]
    const float* __restrict__ bi,  // bias slice [128]
    const float (&x)[4], const float (&h)[HDIM],
    float (&c)[HDIM], float (&hn)[HDIM])
{
#pragma unroll
    for (int j = 0; j < HDIM; ++j) {
        float gi = bi[j];
        float gf = bi[HDIM + j];
        float gg = bi[2 * HDIM + j];
        float go = bi[3 * HDIM + j];
#pragma unroll
        for (int d = 0; d < 4; ++d) {
            float xv = x[d];
            gi += W[(j           ) * 4 + d] * xv;
            gf += W[(HDIM + j    ) * 4 + d] * xv;
            gg += W[(2 * HDIM + j) * 4 + d] * xv;
            go += W[(3 * HDIM + j) * 4 + d] * xv;
        }
#pragma unroll
        for (int k = 0; k < HDIM; ++k) {
            float hv = h[k];
            gi += U[(j           ) * HDIM + k] * hv;
            gf += U[(HDIM + j    ) * HDIM + k] * hv;
            gg += U[(2 * HDIM + j) * HDIM + k] * hv;
            go += U[(3 * HDIM + j) * HDIM + k] * hv;
        }
        float cv = sigm(gf) * c[j] + sigm(gi) * tanh_fast(gg);
        c[j] = cv;
        hn[j] = sigm(go) * tanh_fast(cv);
    }
}

// Layer-1 cell step: 64-wide input split as xa (L0 fwd h) / xb (L0 bwd h).
__device__ __forceinline__ void l1_step(
    const float* __restrict__ W,   // Wih slice [128*64]
    const float* __restrict__ U,   // Whh slice [128*32]
    const float* __restrict__ bi,  // bias slice [128]
    const float (&xa)[HDIM], const float (&xb)[HDIM], const float (&h)[HDIM],
    float (&c)[HDIM], float (&hn)[HDIM])
{
#pragma unroll
    for (int j = 0; j < HDIM; ++j) {
        float gi = bi[j];
        float gf = bi[HDIM + j];
        float gg = bi[2 * HDIM + j];
        float go = bi[3 * HDIM + j];
#pragma unroll
        for (int k = 0; k < HDIM; ++k) {
            float xv = xa[k];
            gi += W[(j           ) * 64 + k] * xv;
            gf += W[(HDIM + j    ) * 64 + k] * xv;
            gg += W[(2 * HDIM + j) * 64 + k] * xv;
            go += W[(3 * HDIM + j) * 64 + k] * xv;
        }
#pragma unroll
        for (int k = 0; k < HDIM; ++k) {
            float xv = xb[k];
            gi += W[(j           ) * 64 + HDIM + k] * xv;
            gf += W[(HDIM + j    ) * 64 + HDIM + k] * xv;
            gg += W[(2 * HDIM + j) * 64 + HDIM + k] * xv;
            go += W[(3 * HDIM + j) * 64 + HDIM + k] * xv;
        }
#pragma unroll
        for (int k = 0; k < HDIM; ++k) {
            float hv = h[k];
            gi += U[(j           ) * HDIM + k] * hv;
            gf += U[(HDIM + j    ) * HDIM + k] * hv;
            gg += U[(2 * HDIM + j) * HDIM + k] * hv;
            go += U[(3 * HDIM + j) * HDIM + k] * hv;
        }
        float cv = sigm(gf) * c[j] + sigm(gi) * tanh_fast(gg);
        c[j] = cv;
        hn[j] = sigm(go) * tanh_fast(cv);
    }
}

__global__ __launch_bounds__(256, 2) void lstm_fused(
    const float* __restrict__ dir_input,   // [32768,6]
    const float* __restrict__ pos,         // [32768,30,4]
    const float* __restrict__ lvl_Wih0, const float* __restrict__ lvl_Whh0,
    const float* __restrict__ lvl_b0,
    const float* __restrict__ lvl_Wih1, const float* __restrict__ lvl_Whh1,
    const float* __restrict__ lvl_b1,
    const float* __restrict__ vor_Wih0, const float* __restrict__ vor_Whh0,
    const float* __restrict__ vor_b0,
    const float* __restrict__ vor_Wih1, const float* __restrict__ vor_Whh1,
    const float* __restrict__ vor_b1,
    const float* __restrict__ lvl_fc_W, const float* __restrict__ lvl_fc_b,
    const float* __restrict__ vor_fc_W, const float* __restrict__ vor_fc_b,
    float* __restrict__ out)               // [32768,2], pre-zeroed
{
    const int m    = blockIdx.y;                       // 0 = lvl, 1 = vor (uniform)
    const int s    = blockIdx.x * 256 + threadIdx.x;   // 0..65535
    const int half = s >> 15;                          // 0 = left, 1 = right
    const int b    = s & 32767;

    const float* Wih0 = m ? vor_Wih0 : lvl_Wih0;   // [2,128,4]
    const float* Whh0 = m ? vor_Whh0 : lvl_Whh0;   // [2,128,32]
    const float* B0   = m ? vor_b0   : lvl_b0;     // [2,128]
    const float* Wih1 = m ? vor_Wih1 : lvl_Wih1;   // [2,128,64]
    const float* Whh1 = m ? vor_Whh1 : lvl_Whh1;   // [2,128,32]
    const float* B1   = m ? vor_b1   : lvl_b1;     // [2,128]

    const float* xbase = pos + ((size_t)b * 30 + half * 15) * 4;

    // Only hb history lives in scratch (dynamic t index), as float4 packets.
    float4 hb4[15 * 8];

    // ---------- Layer 0 backward (t = 14 .. 0) ----------
    {
        float h[HDIM], c[HDIM];
#pragma unroll
        for (int j = 0; j < HDIM; ++j) { h[j] = 0.0f; c[j] = 0.0f; }
#pragma unroll 1
        for (int t = 14; t >= 0; --t) {
            float x[4];
            const float* xp = xbase + t * 4;
#pragma unroll
            for (int d = 0; d < 4; ++d) x[d] = xp[d];
            float hn[HDIM];
            l0_step(Wih0 + 128 * 4, Whh0 + 128 * 32, B0 + 128, x, h, c, hn);
#pragma unroll
            for (int j = 0; j < HDIM; ++j) h[j] = hn[j];
#pragma unroll
            for (int q = 0; q < 8; ++q)
                hb4[t * 8 + q] = make_float4(hn[4 * q], hn[4 * q + 1], hn[4 * q + 2], hn[4 * q + 3]);
        }
    }

    // ---------- L0 fwd + L1 fwd fused scan (t = 0 .. 14) ----------
    float h0[HDIM], c0[HDIM], h1[HDIM], c1[HDIM], hbf[HDIM];
#pragma unroll
    for (int j = 0; j < HDIM; ++j) { h0[j] = 0.0f; c0[j] = 0.0f; h1[j] = 0.0f; c1[j] = 0.0f; }

#pragma unroll 1
    for (int t = 0; t < 15; ++t) {
        float x[4];
        const float* xp = xbase + t * 4;
#pragma unroll
        for (int d = 0; d < 4; ++d) x[d] = xp[d];

        // prefetch this step's bwd hidden early (vmcnt overlap with L0 step)
#pragma unroll
        for (int q = 0; q < 8; ++q) {
            float4 v = hb4[t * 8 + q];
            hbf[4 * q] = v.x; hbf[4 * q + 1] = v.y; hbf[4 * q + 2] = v.z; hbf[4 * q + 3] = v.w;
        }

        float h0n[HDIM];
        l0_step(Wih0, Whh0, B0, x, h0, c0, h0n);
#pragma unroll
        for (int j = 0; j < HDIM; ++j) h0[j] = h0n[j];

        float h1n[HDIM];
        l1_step(Wih1, Whh1, B1, h0, hbf, h1, c1, h1n);
#pragma unroll
        for (int j = 0; j < HDIM; ++j) h1[j] = h1n[j];
    }
    // h0 = L0 fwd h[T-1]; hbf = L0 bwd h[T-1]; h1 = L1 fwd h[T-1].

    // ---------- Layer 1 backward, single step from zero state ----------
    float h1b[HDIM];
    {
        const float* Wb = Wih1 + 128 * 64;   // dir 1
        const float* bb = B1 + 128;
#pragma unroll
        for (int j = 0; j < HDIM; ++j) {
            float gi = bb[j];
            float gg = bb[2 * HDIM + j];
            float go = bb[3 * HDIM + j];
#pragma unroll
            for (int k = 0; k < HDIM; ++k) {
                float xa = h0[k];
                float xb = hbf[k];
                gi += Wb[(j           ) * 64 + k] * xa + Wb[(j           ) * 64 + HDIM + k] * xb;
                gg += Wb[(2 * HDIM + j) * 64 + k] * xa + Wb[(2 * HDIM + j) * 64 + HDIM + k] * xb;
                go += Wb[(3 * HDIM + j) * 64 + k] * xa + Wb[(3 * HDIM + j) * 64 + HDIM + k] * xb;
            }
            float cv = sigm(gi) * tanh_fast(gg);
            h1b[j] = sigm(go) * tanh_fast(cv);
        }
    }

    // ---------- Masks + FC + atomic combine ----------
    const float* dp = dir_input + (size_t)b * 6;
    float mx = dp[0];
    int dmax = 0;
#pragma unroll
    for (int i = 1; i < 6; ++i) {
        float v = dp[i];
        if (v > mx) { mx = v; dmax = i; }
    }

    float o0, o1;
    if (m == 0) {
        float mask = (half == 0) ? ((dmax == 2 || dmax == 3) ? 1.0f : 0.0f)
                                 : ((dmax == 0 || dmax == 5) ? 1.0f : 0.0f);
        float a0 = lvl_fc_b[0];
        float a1 = lvl_fc_b[1];
#pragma unroll
        for (int k = 0; k < HDIM; ++k) {
            a0 += lvl_fc_W[k] * h1[k]      + lvl_fc_W[HDIM + k] * h1b[k];
            a1 += lvl_fc_W[64 + k] * h1[k] + lvl_fc_W[64 + HDIM + k] * h1b[k];
        }
        o0 = a0 * mask;
        o1 = a1 * mask;
    } else {
        float mask = (dmax == 1 || dmax == 4) ? 1.0f : 0.0f;
        int off = half * 64;
        float a0 = (half == 0) ? vor_fc_b[0] : 0.0f;
        float a1 = (half == 0) ? vor_fc_b[1] : 0.0f;
#pragma unroll
        for (int k = 0; k < HDIM; ++k) {
            a0 += vor_fc_W[off + k] * h1[k]       + vor_fc_W[off + HDIM + k] * h1b[k];
            a1 += vor_fc_W[128 + off + k] * h1[k] + vor_fc_W[128 + off + HDIM + k] * h1b[k];
        }
        o0 = a0 * mask;
        o1 = a1 * mask;
    }

    atomicAdd(out + (size_t)b * 2 + 0, o0);
    atomicAdd(out + (size_t)b * 2 + 1, o1);
}

extern "C" void kernel_launch(void* const* d_in, const int* in_sizes, int n_in,
                              void* d_out, int out_size, void* d_ws, size_t ws_size,
                              hipStream_t stream) {
    const float* dir_input = (const float*)d_in[0];
    const float* pos       = (const float*)d_in[1];
    const float* lvl_Wih0  = (const float*)d_in[2];
    const float* lvl_Whh0  = (const float*)d_in[3];
    const float* lvl_b0    = (const float*)d_in[4];
    const float* lvl_Wih1  = (const float*)d_in[5];
    const float* lvl_Whh1  = (const float*)d_in[6];
    const float* lvl_b1    = (const float*)d_in[7];
    const float* vor_Wih0  = (const float*)d_in[8];
    const float* vor_Whh0  = (const float*)d_in[9];
    const float* vor_b0    = (const float*)d_in[10];
    const float* vor_Wih1  = (const float*)d_in[11];
    const float* vor_Whh1  = (const float*)d_in[12];
    const float* vor_b1    = (const float*)d_in[13];
    const float* lvl_fc_W  = (const float*)d_in[14];
    const float* lvl_fc_b  = (const float*)d_in[15];
    const float* vor_fc_W  = (const float*)d_in[16];
    const float* vor_fc_b  = (const float*)d_in[17];
    float* out = (float*)d_out;

    (void)in_sizes; (void)n_in; (void)d_ws; (void)ws_size;

    hipMemsetAsync(d_out, 0, (size_t)out_size * sizeof(float), stream);

    dim3 grid(256, 2, 1);
    dim3 block(256, 1, 1);
    hipLaunchKernelGGL(lstm_fused, grid, block, 0, stream,
                       dir_input, pos,
                       lvl_Wih0, lvl_Whh0, lvl_b0, lvl_Wih1, lvl_Whh1, lvl_b1,
                       vor_Wih0, vor_Whh0, vor_b0, vor_Wih1, vor_Whh1, vor_b1,
                       lvl_fc_W, lvl_fc_b, vor_fc_W, vor_fc_b,
                       out);
}

// Round 3
// 687.055 us; speedup vs baseline: 8.0718x; 8.0718x over previous
//
#include <hip/hip_runtime.h>
#include <hip/hip_bf16.h>

typedef _Float16 f16x8 __attribute__((ext_vector_type(8)));
typedef float    f32x4 __attribute__((ext_vector_type(4)));

__device__ __forceinline__ float sigm(float x) {
    return __fdividef(1.0f, 1.0f + __expf(-x));
}
__device__ __forceinline__ float tanh_fast(float x) {
    return 1.0f - __fdividef(2.0f, 1.0f + __expf(2.0f * x));
}
__device__ __forceinline__ float cell(float i_, float f_, float g_, float o_, float& c) {
    float cv = sigm(f_) * c + sigm(i_) * tanh_fast(g_);
    c = cv;
    return sigm(o_) * tanh_fast(cv);
}

// Load 8 consecutive fp32 at p, convert to packed fp16 B-frag chunk.
__device__ __forceinline__ f16x8 bfrag_k32(const float* __restrict__ p) {
    const float4 w0 = *(const float4*)p;
    const float4 w1 = *(const float4*)(p + 4);
    f16x8 v;
    v[0] = (_Float16)w0.x; v[1] = (_Float16)w0.y; v[2] = (_Float16)w0.z; v[3] = (_Float16)w0.w;
    v[4] = (_Float16)w1.x; v[5] = (_Float16)w1.y; v[6] = (_Float16)w1.z; v[7] = (_Float16)w1.w;
    return v;
}

// ---------------------------------------------------------------------------
// K1: layer-0 scans. grid = (NT/4, 4[model*2+dir]); 1 wave = 16 samples.
// Writes h history (fp16, A-frag-friendly layout) to hist workspace:
//   hist[((m*NT + tile)*15 + t)*1024 + row*64 + dir*32 + k]
// ---------------------------------------------------------------------------
__global__ __launch_bounds__(256, 2) void k1_l0(
    const float* __restrict__ pos,            // [32768,30,4]
    const float* __restrict__ lvl_Wih0, const float* __restrict__ lvl_Whh0,
    const float* __restrict__ lvl_b0,
    const float* __restrict__ vor_Wih0, const float* __restrict__ vor_Whh0,
    const float* __restrict__ vor_b0,
    _Float16* __restrict__ hist, int chunk_base, int NT)
{
    const int lane = threadIdx.x & 63;
    const int wv   = threadIdx.x >> 6;
    const int n0   = lane & 15;
    const int quad = lane >> 4;
    const int tile = blockIdx.x * 4 + wv;
    const int m    = blockIdx.y >> 1;
    const int dir  = blockIdx.y & 1;

    const float* Wih = (m ? vor_Wih0 : lvl_Wih0) + dir * 128 * 4;   // [128][4]
    const float* Whh = (m ? vor_Whh0 : lvl_Whh0) + dir * 128 * 32;  // [128][32]
    const float* bs  = (m ? vor_b0   : lvl_b0)   + dir * 128;       // [128]

    // B-frags (K=32): B[k][n], lane holds n=n0, k=quad*8+r
    f16x8 WhhB[8];
#pragma unroll
    for (int nb = 0; nb < 8; ++nb)
        WhhB[nb] = bfrag_k32(Whh + (nb * 16 + n0) * 32 + quad * 8);

    // Wih B-frags: only k<4 nonzero (quad==0, r<4)
    f16x8 WihB[8];
#pragma unroll
    for (int nb = 0; nb < 8; ++nb) {
        f16x8 v;
#pragma unroll
        for (int r = 0; r < 8; ++r) v[r] = (_Float16)0.0f;
        if (quad == 0) {
            const float4 w = *(const float4*)(Wih + (nb * 16 + n0) * 4);
            v[0] = (_Float16)w.x; v[1] = (_Float16)w.y;
            v[2] = (_Float16)w.z; v[3] = (_Float16)w.w;
        }
        WihB[nb] = v;
    }

    float bias8[8];
#pragma unroll
    for (int nb = 0; nb < 8; ++nb) bias8[nb] = bs[nb * 16 + n0];

    __shared__ _Float16 tb[4][640];          // 16 rows x 40 fp16 (padded), per wave
    _Float16* T = tb[wv];

    const int sbase = chunk_base + tile * 16;   // sample index within model batch

    float c[4][2];
#pragma unroll
    for (int r = 0; r < 4; ++r) { c[r][0] = 0.0f; c[r][1] = 0.0f; }
    f16x8 hfrag;
#pragma unroll
    for (int r = 0; r < 8; ++r) hfrag[r] = (_Float16)0.0f;

    const size_t hist_tile = ((size_t)(m * NT + tile)) * 15 * 1024;

#pragma unroll 1
    for (int ti = 0; ti < 15; ++ti) {
        const int t = dir ? (14 - ti) : ti;

        // x A-frag: A[m=n0][k=r], k<4 (lanes quad==0 only)
        f16x8 xfrag;
#pragma unroll
        for (int r = 0; r < 8; ++r) xfrag[r] = (_Float16)0.0f;
        if (quad == 0) {
            const int s    = sbase + n0;
            const int b    = s & 32767;
            const int half = s >> 15;
            const float4 xv = *(const float4*)(pos + ((size_t)b * 30 + half * 15 + t) * 4);
            xfrag[0] = (_Float16)xv.x; xfrag[1] = (_Float16)xv.y;
            xfrag[2] = (_Float16)xv.z; xfrag[3] = (_Float16)xv.w;
        }

        f32x4 acc[8];
#pragma unroll
        for (int nb = 0; nb < 8; ++nb) {
            f32x4 a; a[0] = bias8[nb]; a[1] = bias8[nb]; a[2] = bias8[nb]; a[3] = bias8[nb];
            acc[nb] = a;
        }
#pragma unroll
        for (int nb = 0; nb < 8; ++nb)
            acc[nb] = __builtin_amdgcn_mfma_f32_16x16x32_f16(xfrag, WihB[nb], acc[nb], 0, 0, 0);
#pragma unroll
        for (int nb = 0; nb < 8; ++nb)
            acc[nb] = __builtin_amdgcn_mfma_f32_16x16x32_f16(hfrag, WhhB[nb], acc[nb], 0, 0, 0);

        // activations: lane owns (4 rows x 2 j) cells, all gates local
#pragma unroll
        for (int r = 0; r < 4; ++r) {
#pragma unroll
            for (int jh = 0; jh < 2; ++jh) {
                float h = cell(acc[jh][r], acc[2 + jh][r], acc[4 + jh][r], acc[6 + jh][r], c[r][jh]);
                T[(quad * 4 + r) * 40 + jh * 16 + n0] = (_Float16)h;
            }
        }
        // C-layout -> A-frag transpose readback
        hfrag = *(const f16x8*)(T + n0 * 40 + quad * 8);

        // store to global history
        *(f16x8*)(hist + hist_tile + (size_t)t * 1024 + n0 * 64 + dir * 32 + quad * 8) = hfrag;
    }
}

// ---------------------------------------------------------------------------
// K2: layer-1 fwd scan + 1-step bwd + FC/mask epilogue.
// grid = (NT/4, 2[model]); 1 wave = 16 samples.
// ---------------------------------------------------------------------------
__global__ __launch_bounds__(256, 2) void k2_l1(
    const float* __restrict__ dir_input,      // [32768,6]
    const float* __restrict__ lvl_Wih1, const float* __restrict__ lvl_Whh1,
    const float* __restrict__ lvl_b1,
    const float* __restrict__ vor_Wih1, const float* __restrict__ vor_Whh1,
    const float* __restrict__ vor_b1,
    const float* __restrict__ lvl_fc_W, const float* __restrict__ lvl_fc_b,
    const float* __restrict__ vor_fc_W, const float* __restrict__ vor_fc_b,
    const _Float16* __restrict__ hist, float* __restrict__ out,
    int chunk_base, int NT)
{
    const int lane = threadIdx.x & 63;
    const int wv   = threadIdx.x >> 6;
    const int n0   = lane & 15;
    const int quad = lane >> 4;
    const int tile = blockIdx.x * 4 + wv;
    const int m    = blockIdx.y;

    const float* Wih = m ? vor_Wih1 : lvl_Wih1;   // [2][128][64]
    const float* Whh = m ? vor_Whh1 : lvl_Whh1;   // [2][128][32]
    const float* bs  = m ? vor_b1   : lvl_b1;     // [2][128]

    f16x8 WA[8], WB[8], WH[8];
#pragma unroll
    for (int nb = 0; nb < 8; ++nb) {
        const int col = nb * 16 + n0;
        WA[nb] = bfrag_k32(Wih + col * 64 + quad * 8);        // x part a (h0 fwd)
        WB[nb] = bfrag_k32(Wih + col * 64 + 32 + quad * 8);   // x part b (h0 bwd)
        WH[nb] = bfrag_k32(Whh + col * 32 + quad * 8);        // recurrent
    }
    float bias8[8];
#pragma unroll
    for (int nb = 0; nb < 8; ++nb) bias8[nb] = bs[nb * 16 + n0];

    __shared__ _Float16 tb[4][640];
    _Float16* T = tb[wv];

    const _Float16* hb = hist + ((size_t)(m * NT + tile)) * 15 * 1024;

    float c1[4][2];
#pragma unroll
    for (int r = 0; r < 4; ++r) { c1[r][0] = 0.0f; c1[r][1] = 0.0f; }
    f16x8 h1frag;
#pragma unroll
    for (int r = 0; r < 8; ++r) h1frag[r] = (_Float16)0.0f;
    float h1f[4][2];

#pragma unroll 1
    for (int t = 0; t < 15; ++t) {
        const _Float16* hp = hb + (size_t)t * 1024 + n0 * 64 + quad * 8;
        const f16x8 a_f = *(const f16x8*)hp;          // h0 fwd, k=quad*8..+7
        const f16x8 a_b = *(const f16x8*)(hp + 32);   // h0 bwd

        f32x4 acc[8];
#pragma unroll
        for (int nb = 0; nb < 8; ++nb) {
            f32x4 a; a[0] = bias8[nb]; a[1] = bias8[nb]; a[2] = bias8[nb]; a[3] = bias8[nb];
            acc[nb] = a;
        }
#pragma unroll
        for (int nb = 0; nb < 8; ++nb)
            acc[nb] = __builtin_amdgcn_mfma_f32_16x16x32_f16(a_f, WA[nb], acc[nb], 0, 0, 0);
#pragma unroll
        for (int nb = 0; nb < 8; ++nb)
            acc[nb] = __builtin_amdgcn_mfma_f32_16x16x32_f16(a_b, WB[nb], acc[nb], 0, 0, 0);
#pragma unroll
        for (int nb = 0; nb < 8; ++nb)
            acc[nb] = __builtin_amdgcn_mfma_f32_16x16x32_f16(h1frag, WH[nb], acc[nb], 0, 0, 0);

#pragma unroll
        for (int r = 0; r < 4; ++r) {
#pragma unroll
            for (int jh = 0; jh < 2; ++jh) {
                float h = cell(acc[jh][r], acc[2 + jh][r], acc[4 + jh][r], acc[6 + jh][r], c1[r][jh]);
                h1f[r][jh] = h;
                T[(quad * 4 + r) * 40 + jh * 16 + n0] = (_Float16)h;
            }
        }
        h1frag = *(const f16x8*)(T + n0 * 40 + quad * 8);
    }

    // ---- L1 backward, single step from zero state (f-gate dropped) ----
    float h1b[4][2];
    {
        const float* Wb = Wih + 128 * 64;   // dir 1
        const float* bb = bs + 128;
        const _Float16* hp14 = hb + (size_t)14 * 1024 + n0 * 64 + quad * 8;
        const f16x8 xa = *(const f16x8*)hp14;
        const f16x8 xb = *(const f16x8*)(hp14 + 32);

        const int nbs[6] = {0, 1, 4, 5, 6, 7};   // i, g, o col-blocks
        f32x4 accb[6];
#pragma unroll
        for (int q = 0; q < 6; ++q) {
            const int col = nbs[q] * 16 + n0;
            const f16x8 wa = bfrag_k32(Wb + col * 64 + quad * 8);
            const f16x8 wb = bfrag_k32(Wb + col * 64 + 32 + quad * 8);
            f32x4 a;
            const float bv = bb[col];
            a[0] = bv; a[1] = bv; a[2] = bv; a[3] = bv;
            a = __builtin_amdgcn_mfma_f32_16x16x32_f16(xa, wa, a, 0, 0, 0);
            a = __builtin_amdgcn_mfma_f32_16x16x32_f16(xb, wb, a, 0, 0, 0);
            accb[q] = a;
        }
#pragma unroll
        for (int r = 0; r < 4; ++r) {
#pragma unroll
            for (int jh = 0; jh < 2; ++jh) {
                const float i_ = accb[jh][r], g_ = accb[2 + jh][r], o_ = accb[4 + jh][r];
                const float cv = sigm(i_) * tanh_fast(g_);
                h1b[r][jh] = sigm(o_) * tanh_fast(cv);
            }
        }
    }

    // ---- FC + masks + atomic combine ----
    const int half = (chunk_base + tile * 16) >> 15;   // wave-uniform

    float p[4][2];
    {
        float wf[2][2], wk[2][2];
        if (m == 0) {
#pragma unroll
            for (int o = 0; o < 2; ++o)
#pragma unroll
                for (int jh = 0; jh < 2; ++jh) {
                    wf[o][jh] = lvl_fc_W[o * 64 + jh * 16 + n0];
                    wk[o][jh] = lvl_fc_W[o * 64 + 32 + jh * 16 + n0];
                }
        } else {
#pragma unroll
            for (int o = 0; o < 2; ++o)
#pragma unroll
                for (int jh = 0; jh < 2; ++jh) {
                    wf[o][jh] = vor_fc_W[o * 128 + half * 64 + jh * 16 + n0];
                    wk[o][jh] = vor_fc_W[o * 128 + half * 64 + 32 + jh * 16 + n0];
                }
        }
#pragma unroll
        for (int r = 0; r < 4; ++r)
#pragma unroll
            for (int o = 0; o < 2; ++o)
                p[r][o] = wf[o][0] * h1f[r][0] + wf[o][1] * h1f[r][1]
                        + wk[o][0] * h1b[r][0] + wk[o][1] * h1b[r][1];
        // reduce over the 16 lanes of each quad (masks < 16 stay in-quad)
#pragma unroll
        for (int mask = 1; mask < 16; mask <<= 1)
#pragma unroll
            for (int r = 0; r < 4; ++r)
#pragma unroll
                for (int o = 0; o < 2; ++o)
                    p[r][o] += __shfl_xor(p[r][o], mask);
    }

    if (n0 < 4) {
        const int r   = n0;
        const int s   = chunk_base + tile * 16 + quad * 4 + r;
        const int b   = s & 32767;
        const float* dp = dir_input + (size_t)b * 6;
        float mx = dp[0];
        int dmax = 0;
#pragma unroll
        for (int i = 1; i < 6; ++i) {
            const float v = dp[i];
            if (v > mx) { mx = v; dmax = i; }
        }
        float mask, b0v, b1v;
        if (m == 0) {
            mask = (half == 0) ? ((dmax == 2 || dmax == 3) ? 1.0f : 0.0f)
                               : ((dmax == 0 || dmax == 5) ? 1.0f : 0.0f);
            b0v = lvl_fc_b[0]; b1v = lvl_fc_b[1];
        } else {
            mask = (dmax == 1 || dmax == 4) ? 1.0f : 0.0f;
            b0v = (half == 0) ? vor_fc_b[0] : 0.0f;
            b1v = (half == 0) ? vor_fc_b[1] : 0.0f;
        }
        atomicAdd(out + (size_t)b * 2 + 0, (p[r][0] + b0v) * mask);
        atomicAdd(out + (size_t)b * 2 + 1, (p[r][1] + b1v) * mask);
    }
}

extern "C" void kernel_launch(void* const* d_in, const int* in_sizes, int n_in,
                              void* d_out, int out_size, void* d_ws, size_t ws_size,
                              hipStream_t stream) {
    const float* dir_input = (const float*)d_in[0];
    const float* pos       = (const float*)d_in[1];
    const float* lvl_Wih0  = (const float*)d_in[2];
    const float* lvl_Whh0  = (const float*)d_in[3];
    const float* lvl_b0    = (const float*)d_in[4];
    const float* lvl_Wih1  = (const float*)d_in[5];
    const float* lvl_Whh1  = (const float*)d_in[6];
    const float* lvl_b1    = (const float*)d_in[7];
    const float* vor_Wih0  = (const float*)d_in[8];
    const float* vor_Whh0  = (const float*)d_in[9];
    const float* vor_b0    = (const float*)d_in[10];
    const float* vor_Wih1  = (const float*)d_in[11];
    const float* vor_Whh1  = (const float*)d_in[12];
    const float* vor_b1    = (const float*)d_in[13];
    const float* lvl_fc_W  = (const float*)d_in[14];
    const float* lvl_fc_b  = (const float*)d_in[15];
    const float* vor_fc_W  = (const float*)d_in[16];
    const float* vor_fc_b  = (const float*)d_in[17];
    float* out = (float*)d_out;
    _Float16* hist = (_Float16*)d_ws;

    (void)in_sizes; (void)n_in;

    hipMemsetAsync(d_out, 0, (size_t)out_size * sizeof(float), stream);

    // per sample-index: 2 models * 15 t * 64 k * 2 B = 3840 B of history
    int S_C = 16384;                                   // 63 MB chunk (L3-friendly)
    while ((size_t)S_C * 3840ull > ws_size && S_C > 64) S_C >>= 1;

    for (int base = 0; base < 65536; base += S_C) {
        const int NT = S_C / 16;
        dim3 blk(256, 1, 1);
        dim3 g1(NT / 4, 4, 1);
        hipLaunchKernelGGL(k1_l0, g1, blk, 0, stream,
                           pos, lvl_Wih0, lvl_Whh0, lvl_b0,
                           vor_Wih0, vor_Whh0, vor_b0,
                           hist, base, NT);
        dim3 g2(NT / 4, 2, 1);
        hipLaunchKernelGGL(k2_l1, g2, blk, 0, stream,
                           dir_input, lvl_Wih1, lvl_Whh1, lvl_b1,
                           vor_Wih1, vor_Whh1, vor_b1,
                           lvl_fc_W, lvl_fc_b, vor_fc_W, vor_fc_b,
                           hist, out, base, NT);
    }
}

// Round 4
// 381.733 us; speedup vs baseline: 14.5279x; 1.7998x over previous
//
#include <hip/hip_runtime.h>
#include <hip/hip_bf16.h>

typedef _Float16 f16x8 __attribute__((ext_vector_type(8)));
typedef _Float16 f16x2 __attribute__((ext_vector_type(2)));
typedef float    f32x4 __attribute__((ext_vector_type(4)));

#define LOG2E  1.44269504f
#define LOG2E2 2.88539008f

// Fused LSTM cell: c' = sigm(f)c + sigm(i)tanh(g); h = sigm(o)tanh(c')
// via A=1+2^(-f·log2e), B=1+2^(-i·log2e), C=1+2^(2g·log2e):
//   c' = c·rcp(A) + (C-2)·rcp(B·C);  h = (E-2)·rcp(D·E)
// 5 exp2 + 3 rcp (vs 5 exp + 5 rcp + libm fixups). Bounded gates -> no overflow.
__device__ __forceinline__ float cell2(float i_, float f_, float g_, float o_, float& c) {
    float A  = 1.0f + __builtin_amdgcn_exp2f(-LOG2E * f_);
    float Bv = 1.0f + __builtin_amdgcn_exp2f(-LOG2E * i_);
    float Cv = 1.0f + __builtin_amdgcn_exp2f(LOG2E2 * g_);
    float cn = c * __builtin_amdgcn_rcpf(A) + (Cv - 2.0f) * __builtin_amdgcn_rcpf(Bv * Cv);
    c = cn;
    float D  = 1.0f + __builtin_amdgcn_exp2f(-LOG2E * o_);
    float E  = 1.0f + __builtin_amdgcn_exp2f(LOG2E2 * cn);
    return (E - 2.0f) * __builtin_amdgcn_rcpf(D * E);
}

__device__ __forceinline__ f16x8 bfrag8(const float* __restrict__ p) {
    const float4 w0 = *(const float4*)p;
    const float4 w1 = *(const float4*)(p + 4);
    f16x8 v;
    v[0] = (_Float16)w0.x; v[1] = (_Float16)w0.y; v[2] = (_Float16)w0.z; v[3] = (_Float16)w0.w;
    v[4] = (_Float16)w1.x; v[5] = (_Float16)w1.y; v[6] = (_Float16)w1.z; v[7] = (_Float16)w1.w;
    return v;
}

// ---------------------------------------------------------------------------
// K1: layer-0 scans. grid = (NT/4, 4[model*2+dir]); 1 wave = 16 samples.
// Column perm: acc block nb=2g+p holds gate g, j = 2*n0+p  (adjacent pairs).
// hist layout: hist[(m*NT+tile)*15*1024 + t*1024 + dir*512 + lane*8], f16x8.
// ---------------------------------------------------------------------------
__global__ __launch_bounds__(256, 3) void k1_l0(
    const float* __restrict__ pos,            // [32768,30,4]
    const float* __restrict__ lvl_Wih0, const float* __restrict__ lvl_Whh0,
    const float* __restrict__ lvl_b0,
    const float* __restrict__ vor_Wih0, const float* __restrict__ vor_Whh0,
    const float* __restrict__ vor_b0,
    _Float16* __restrict__ hist, int chunk_base, int NT)
{
    const int lane = threadIdx.x & 63;
    const int wv   = threadIdx.x >> 6;
    const int n0   = lane & 15;
    const int quad = lane >> 4;
    const int tile = blockIdx.x * 4 + wv;
    const int m    = blockIdx.y >> 1;
    const int dir  = blockIdx.y & 1;

    const float* Wih = (m ? vor_Wih0 : lvl_Wih0) + dir * 128 * 4;   // [128][4]
    const float* Whh = (m ? vor_Whh0 : lvl_Whh0) + dir * 128 * 32;  // [128][32]
    const float* bs  = (m ? vor_b0   : lvl_b0)   + dir * 128;       // [128]

    f16x8 WhhB[8], WihB[8];
#pragma unroll
    for (int nb = 0; nb < 8; ++nb) {
        const int row = (nb >> 1) * 32 + 2 * n0 + (nb & 1);   // permuted column
        WhhB[nb] = bfrag8(Whh + row * 32 + quad * 8);         // k = quad*8+r
        f16x8 v;
#pragma unroll
        for (int r = 0; r < 8; ++r) v[r] = (_Float16)0.0f;
        if (quad == 0) {                                      // k<4: Wih, k==4: bias
            const float4 w = *(const float4*)(Wih + row * 4);
            v[0] = (_Float16)w.x; v[1] = (_Float16)w.y;
            v[2] = (_Float16)w.z; v[3] = (_Float16)w.w;
            v[4] = (_Float16)bs[row];
        }
        WihB[nb] = v;
    }

    __shared__ _Float16 tb[4][640];            // 16 rows x 40 f16 / wave
    _Float16* T = tb[wv];

    const int s    = chunk_base + tile * 16 + n0;
    const int b    = s & 32767;
    const int half = s >> 15;
    const float* xp = pos + ((size_t)b * 30 + half * 15 + (dir ? 14 : 0)) * 4;
    const int xstep = dir ? -4 : 4;

    _Float16* hp = hist + ((size_t)(m * NT + tile)) * 15 * 1024
                 + (size_t)(dir ? 14 : 0) * 1024 + dir * 512 + lane * 8;
    const int hstep = dir ? -1024 : 1024;

    float c[4][2];
#pragma unroll
    for (int r = 0; r < 4; ++r) { c[r][0] = 0.0f; c[r][1] = 0.0f; }
    f16x8 hfrag;
#pragma unroll
    for (int r = 0; r < 8; ++r) hfrag[r] = (_Float16)0.0f;
    f16x8 xfrag;
#pragma unroll
    for (int r = 0; r < 8; ++r) xfrag[r] = (_Float16)0.0f;
    xfrag[4] = (_Float16)1.0f;                 // bias slot (k=4)

    const f32x4 z4 = {0.0f, 0.0f, 0.0f, 0.0f};

#pragma unroll 1
    for (int ti = 0; ti < 15; ++ti) {
        // all lanes load sample n0's x; lanes quad!=0 multiply zero weights
        const float4 xv = *(const float4*)xp;
        xp += xstep;
        xfrag[0] = (_Float16)xv.x; xfrag[1] = (_Float16)xv.y;
        xfrag[2] = (_Float16)xv.z; xfrag[3] = (_Float16)xv.w;

        f32x4 acc[8];
#pragma unroll
        for (int nb = 0; nb < 8; ++nb)
            acc[nb] = __builtin_amdgcn_mfma_f32_16x16x32_f16(xfrag, WihB[nb], z4, 0, 0, 0);
#pragma unroll
        for (int nb = 0; nb < 8; ++nb)
            acc[nb] = __builtin_amdgcn_mfma_f32_16x16x32_f16(hfrag, WhhB[nb], acc[nb], 0, 0, 0);

#pragma unroll
        for (int r = 0; r < 4; ++r) {
            f16x2 pk;
#pragma unroll
            for (int p = 0; p < 2; ++p) {
                float h = cell2(acc[0 + p][r], acc[2 + p][r], acc[4 + p][r], acc[6 + p][r], c[r][p]);
                pk[p] = (_Float16)h;
            }
            *(f16x2*)(T + (quad * 4 + r) * 40 + 2 * n0) = pk;   // packed b32, 2-way banks
        }
        hfrag = *(const f16x8*)(T + n0 * 40 + quad * 8);        // A-frag readback
        *(f16x8*)hp = hfrag;                                    // lane-contiguous 16B
        hp += hstep;
    }
}

// ---------------------------------------------------------------------------
// K2: layer-1 fwd scan + 1-step bwd + FC/mask epilogue. grid = (NT/4, 2).
// ---------------------------------------------------------------------------
__global__ __launch_bounds__(256, 2) void k2_l1(
    const float* __restrict__ dir_input,      // [32768,6]
    const float* __restrict__ lvl_Wih1, const float* __restrict__ lvl_Whh1,
    const float* __restrict__ lvl_b1,
    const float* __restrict__ vor_Wih1, const float* __restrict__ vor_Whh1,
    const float* __restrict__ vor_b1,
    const float* __restrict__ lvl_fc_W, const float* __restrict__ lvl_fc_b,
    const float* __restrict__ vor_fc_W, const float* __restrict__ vor_fc_b,
    const _Float16* __restrict__ hist, float* __restrict__ out,
    int chunk_base, int NT)
{
    const int lane = threadIdx.x & 63;
    const int wv   = threadIdx.x >> 6;
    const int n0   = lane & 15;
    const int quad = lane >> 4;
    const int tile = blockIdx.x * 4 + wv;
    const int m    = blockIdx.y;

    const float* Wih = m ? vor_Wih1 : lvl_Wih1;   // [2][128][64]
    const float* Whh = m ? vor_Whh1 : lvl_Whh1;   // [2][128][32]
    const float* bs  = m ? vor_b1   : lvl_b1;     // [2][128]

    f16x8 WA[8], WB[8], WH[8];
    float bias8[8];
#pragma unroll
    for (int nb = 0; nb < 8; ++nb) {
        const int row = (nb >> 1) * 32 + 2 * n0 + (nb & 1);
        WA[nb] = bfrag8(Wih + row * 64 + quad * 8);
        WB[nb] = bfrag8(Wih + row * 64 + 32 + quad * 8);
        WH[nb] = bfrag8(Whh + row * 32 + quad * 8);
        bias8[nb] = bs[row];
    }

    __shared__ _Float16 tb[4][640];
    _Float16* T = tb[wv];

    const _Float16* hb = hist + ((size_t)(m * NT + tile)) * 15 * 1024 + lane * 8;

    float c1[4][2];
#pragma unroll
    for (int r = 0; r < 4; ++r) { c1[r][0] = 0.0f; c1[r][1] = 0.0f; }
    f16x8 h1frag;
#pragma unroll
    for (int r = 0; r < 8; ++r) h1frag[r] = (_Float16)0.0f;
    float h1f[4][2];
    f16x8 a_f, a_b;

#pragma unroll 1
    for (int t = 0; t < 15; ++t) {
        a_f = *(const f16x8*)hb;
        a_b = *(const f16x8*)(hb + 512);
        hb += 1024;

        f32x4 acc[8];
#pragma unroll
        for (int nb = 0; nb < 8; ++nb) {
            f32x4 a;
            a[0] = bias8[nb]; a[1] = bias8[nb]; a[2] = bias8[nb]; a[3] = bias8[nb];
            acc[nb] = __builtin_amdgcn_mfma_f32_16x16x32_f16(a_f, WA[nb], a, 0, 0, 0);
        }
#pragma unroll
        for (int nb = 0; nb < 8; ++nb)
            acc[nb] = __builtin_amdgcn_mfma_f32_16x16x32_f16(a_b, WB[nb], acc[nb], 0, 0, 0);
#pragma unroll
        for (int nb = 0; nb < 8; ++nb)
            acc[nb] = __builtin_amdgcn_mfma_f32_16x16x32_f16(h1frag, WH[nb], acc[nb], 0, 0, 0);

#pragma unroll
        for (int r = 0; r < 4; ++r) {
            f16x2 pk;
#pragma unroll
            for (int p = 0; p < 2; ++p) {
                float h = cell2(acc[0 + p][r], acc[2 + p][r], acc[4 + p][r], acc[6 + p][r], c1[r][p]);
                h1f[r][p] = h;
                pk[p] = (_Float16)h;
            }
            *(f16x2*)(T + (quad * 4 + r) * 40 + 2 * n0) = pk;
        }
        h1frag = *(const f16x8*)(T + n0 * 40 + quad * 8);
    }
    // a_f/a_b still hold t=14 (input to the 1-step L1 backward).

    float h1b[4][2];
    {
        const float* Wb = Wih + 128 * 64;   // dir 1
        const float* bb = bs + 128;
        const int gsel[3] = {0, 2, 3};      // i, g, o (f-gate dead: c=0)
        f32x4 accb[6];
#pragma unroll
        for (int q = 0; q < 6; ++q) {
            const int row = gsel[q >> 1] * 32 + 2 * n0 + (q & 1);
            const f16x8 wa = bfrag8(Wb + row * 64 + quad * 8);
            const f16x8 wb = bfrag8(Wb + row * 64 + 32 + quad * 8);
            f32x4 a;
            const float bv = bb[row];
            a[0] = bv; a[1] = bv; a[2] = bv; a[3] = bv;
            a = __builtin_amdgcn_mfma_f32_16x16x32_f16(a_f, wa, a, 0, 0, 0);
            a = __builtin_amdgcn_mfma_f32_16x16x32_f16(a_b, wb, a, 0, 0, 0);
            accb[q] = a;
        }
#pragma unroll
        for (int r = 0; r < 4; ++r) {
#pragma unroll
            for (int p = 0; p < 2; ++p) {
                const float i_ = accb[p][r], g_ = accb[2 + p][r], o_ = accb[4 + p][r];
                float Bv = 1.0f + __builtin_amdgcn_exp2f(-LOG2E * i_);
                float Cv = 1.0f + __builtin_amdgcn_exp2f(LOG2E2 * g_);
                float cv = (Cv - 2.0f) * __builtin_amdgcn_rcpf(Bv * Cv);
                float D  = 1.0f + __builtin_amdgcn_exp2f(-LOG2E * o_);
                float E  = 1.0f + __builtin_amdgcn_exp2f(LOG2E2 * cv);
                h1b[r][p] = (E - 2.0f) * __builtin_amdgcn_rcpf(D * E);
            }
        }
    }

    // ---- FC + masks + atomic combine (perm: lane n0 owns j = 2n0, 2n0+1) ----
    const int half = (chunk_base + tile * 16) >> 15;   // wave-uniform

    float pr[4][2];
    {
        float wf[2][2], wk[2][2];
#pragma unroll
        for (int o = 0; o < 2; ++o)
#pragma unroll
            for (int p = 0; p < 2; ++p) {
                if (m == 0) {
                    wf[o][p] = lvl_fc_W[o * 64 + 2 * n0 + p];
                    wk[o][p] = lvl_fc_W[o * 64 + 32 + 2 * n0 + p];
                } else {
                    wf[o][p] = vor_fc_W[o * 128 + half * 64 + 2 * n0 + p];
                    wk[o][p] = vor_fc_W[o * 128 + half * 64 + 32 + 2 * n0 + p];
                }
            }
#pragma unroll
        for (int r = 0; r < 4; ++r)
#pragma unroll
            for (int o = 0; o < 2; ++o)
                pr[r][o] = wf[o][0] * h1f[r][0] + wf[o][1] * h1f[r][1]
                         + wk[o][0] * h1b[r][0] + wk[o][1] * h1b[r][1];
#pragma unroll
        for (int mask = 1; mask < 16; mask <<= 1)
#pragma unroll
            for (int r = 0; r < 4; ++r)
#pragma unroll
                for (int o = 0; o < 2; ++o)
                    pr[r][o] += __shfl_xor(pr[r][o], mask);
    }

    if (n0 < 4) {
        const int r  = n0;
        const int sb = chunk_base + tile * 16 + quad * 4 + r;
        const int b  = sb & 32767;
        const float* dp = dir_input + (size_t)b * 6;
        float mx = dp[0];
        int dmax = 0;
#pragma unroll
        for (int i = 1; i < 6; ++i) {
            const float v = dp[i];
            if (v > mx) { mx = v; dmax = i; }
        }
        float mask, b0v, b1v;
        if (m == 0) {
            mask = (half == 0) ? ((dmax == 2 || dmax == 3) ? 1.0f : 0.0f)
                               : ((dmax == 0 || dmax == 5) ? 1.0f : 0.0f);
            b0v = lvl_fc_b[0]; b1v = lvl_fc_b[1];
        } else {
            mask = (dmax == 1 || dmax == 4) ? 1.0f : 0.0f;
            b0v = (half == 0) ? vor_fc_b[0] : 0.0f;
            b1v = (half == 0) ? vor_fc_b[1] : 0.0f;
        }
        atomicAdd(out + (size_t)b * 2 + 0, (pr[r][0] + b0v) * mask);
        atomicAdd(out + (size_t)b * 2 + 1, (pr[r][1] + b1v) * mask);
    }
}

extern "C" void kernel_launch(void* const* d_in, const int* in_sizes, int n_in,
                              void* d_out, int out_size, void* d_ws, size_t ws_size,
                              hipStream_t stream) {
    const float* dir_input = (const float*)d_in[0];
    const float* pos       = (const float*)d_in[1];
    const float* lvl_Wih0  = (const float*)d_in[2];
    const float* lvl_Whh0  = (const float*)d_in[3];
    const float* lvl_b0    = (const float*)d_in[4];
    const float* lvl_Wih1  = (const float*)d_in[5];
    const float* lvl_Whh1  = (const float*)d_in[6];
    const float* lvl_b1    = (const float*)d_in[7];
    const float* vor_Wih0  = (const float*)d_in[8];
    const float* vor_Whh0  = (const float*)d_in[9];
    const float* vor_b0    = (const float*)d_in[10];
    const float* vor_Wih1  = (const float*)d_in[11];
    const float* vor_Whh1  = (const float*)d_in[12];
    const float* vor_b1    = (const float*)d_in[13];
    const float* lvl_fc_W  = (const float*)d_in[14];
    const float* lvl_fc_b  = (const float*)d_in[15];
    const float* vor_fc_W  = (const float*)d_in[16];
    const float* vor_fc_b  = (const float*)d_in[17];
    float* out = (float*)d_out;
    _Float16* hist = (_Float16*)d_ws;

    (void)in_sizes; (void)n_in;

    hipMemsetAsync(d_out, 0, (size_t)out_size * sizeof(float), stream);

    // per sample: 2 models * 15 t * 64 k * 2 B = 3840 B of history
    int S_C = 32768;                                   // 126 MB chunk (L3-resident)
    while ((size_t)S_C * 3840ull > ws_size && S_C > 64) S_C >>= 1;

    for (int base = 0; base < 65536; base += S_C) {
        const int NT = S_C / 16;
        dim3 blk(256, 1, 1);
        dim3 g1(NT / 4, 4, 1);
        hipLaunchKernelGGL(k1_l0, g1, blk, 0, stream,
                           pos, lvl_Wih0, lvl_Whh0, lvl_b0,
                           vor_Wih0, vor_Whh0, vor_b0,
                           hist, base, NT);
        dim3 g2(NT / 4, 2, 1);
        hipLaunchKernelGGL(k2_l1, g2, blk, 0, stream,
                           dir_input, lvl_Wih1, lvl_Whh1, lvl_b1,
                           vor_Wih1, vor_Whh1, vor_b1,
                           lvl_fc_W, lvl_fc_b, vor_fc_W, vor_fc_b,
                           hist, out, base, NT);
    }
}